// Round 13
// baseline (176.151 us; speedup 1.0000x reference)
//
#include <hip/hip_runtime.h>

#define NN     4096
#define TT     3
#define DD     20
#define EE     131072
#define ADIM   128
#define NEG    0.2f
#define NEDGE  (TT * EE)               // 393216 edges
#define CAP    512                     // bucket segment per row (max used ~260)
#define CSTR   16                      // cnt stride in u32 -> one 64B line per row
#define NBLK   256                     // <= 1 block per CU: ALWAYS co-resident
#define NTHR   512
#define NWAVE  8
#define RPB    16                      // rows per block
#define RPW    2                       // rows per wave

// ---- device-scope arrive/spin barrier (cumulative counter, no reset) --------
__device__ __forceinline__ void gbar(unsigned int* bar, unsigned int phase) {
    __syncthreads();                               // drains block's vmcnt (stores in L2)
    if (threadIdx.x == 0) {
        __threadfence();                           // agent release: L2 writeback
        unsigned int arrived = __hip_atomic_fetch_add(&bar[0], 1u, __ATOMIC_ACQ_REL,
                                                      __HIP_MEMORY_SCOPE_AGENT) + 1u;
        if (arrived == NBLK * phase) {
            __hip_atomic_store(&bar[1], phase, __ATOMIC_RELEASE,
                               __HIP_MEMORY_SCOPE_AGENT);
        } else {
            while (__hip_atomic_load(&bar[1], __ATOMIC_ACQUIRE,
                                     __HIP_MEMORY_SCOPE_AGENT) < phase)
                __builtin_amdgcn_s_sleep(2);
        }
        __threadfence();                           // acquire side: invalidate stale
    }
    __syncthreads();
}

// ---- the whole pipeline in one kernel ---------------------------------------
__global__ __launch_bounds__(NTHR) void k_fused(const int* __restrict__ el,
                                                unsigned int* __restrict__ cnt,
                                                unsigned int* __restrict__ bar,
                                                unsigned short* __restrict__ bucket,
                                                const float* __restrict__ inputs,
                                                const float* __restrict__ lin_w,
                                                const float* __restrict__ lin_b,
                                                const float* __restrict__ edge_emb,
                                                const float* __restrict__ att_w,
                                                float* __restrict__ s0,
                                                float* __restrict__ s1,
                                                float* __restrict__ out) {
    __shared__ unsigned int mask[RPB][512];        // 32 KB persistent nibble-masks
    __shared__ float lut0[8], lut1[8], wc[4], Sred[NWAVE];
    int tid = threadIdx.x, bid = blockIdx.x;
    int wid = tid >> 6, lane = tid & 63;
    int gid = bid * NTHR + tid;                    // 131072 threads

    // ================= P0: s0 init + edge scatter =============================
    #pragma unroll
    for (int r = 0; r < RPW; r++) {
        int row = bid * RPB + wid * RPW + r;
        const float* rp = inputs + row * ADIM;
        float v = rp[lane] * lin_w[lane] + rp[lane + 64] * lin_w[lane + 64];
        #pragma unroll
        for (int off = 32; off > 0; off >>= 1) v += __shfl_down(v, off);
        if (lane == 0) s0[row] = v + lin_b[0];
    }
    #pragma unroll
    for (int rep = 0; rep < 3; rep++) {            // 3 * 131072 = NEDGE exactly
        int i = gid + rep * (NBLK * NTHR);
        int t = i >> 17;                           // EE = 2^17
        int e = i & (EE - 1);
        unsigned int a = (unsigned int)el[(t * 2) * EE + e];
        unsigned int b = (unsigned int)el[(t * 2 + 1) * EE + e];
        unsigned int ts = (unsigned int)t << 12;
        unsigned int ra = atomicAdd(&cnt[a * CSTR], 1u);
        if (ra < CAP) bucket[a * CAP + ra] = (unsigned short)(b | ts);
        unsigned int rb = atomicAdd(&cnt[b * CSTR], 1u);
        if (rb < CAP) bucket[b * CAP + rb] = (unsigned short)(a | ts);
    }
    gbar(bar, 1u);

    // ================= P1: layer 0 (build masks once, scan) ===================
    if (tid < 16) {
        int h = tid >> 3, m = tid & 7;
        const float* w = att_w + h * (DD + 2);     // layer 0
        float e0 = 0.f, e1 = 0.f, e2 = 0.f;
        #pragma unroll
        for (int d = 0; d < DD; d++) {
            float wd = w[1 + d];
            e0 += edge_emb[0 * DD + d] * wd;
            e1 += edge_emb[1 * DD + d] * wd;
            e2 += edge_emb[2 * DD + d] * wd;
        }
        float l = (m & 1 ? e0 : 0.f) + (m & 2 ? e1 : 0.f) + (m & 4 ? e2 : 0.f);
        if (h) lut1[m] = l; else lut0[m] = l;
        if (m == 0) { wc[h] = w[0]; wc[2 + h] = w[DD + 1]; }
    }
    float ps = 0.f;                                // S = sum(s0), deterministic
    for (int j = tid; j < NN; j += NTHR) ps += s0[j];
    #pragma unroll
    for (int off = 32; off > 0; off >>= 1) ps += __shfl_down(ps, off);
    if (lane == 0) Sred[wid] = ps;

    #pragma unroll
    for (int r = 0; r < RPW; r++) {                // build both rows' masks
        int mrow = wid * RPW + r;
        #pragma unroll
        for (int k = 0; k < 8; k++) mask[mrow][k * 64 + lane] = 0u;
        int row = bid * RPB + mrow;
        unsigned int n = min(cnt[row * CSTR], (unsigned int)CAP);
        const unsigned short* brow = bucket + (size_t)row * CAP;
        for (unsigned int i = lane; i < n; i += 64) {
            unsigned int v = brow[i];
            unsigned int col = v & 0xFFFu, t = v >> 12;
            atomicOr(&mask[mrow][col >> 3], 1u << (((col & 7u) << 2) + t));
        }
    }
    __syncthreads();                               // covers lut/Sred (masks wave-local)
    {
        float S = 0.f;
        #pragma unroll
        for (int q = 0; q < NWAVE; q++) S += Sred[q];
        #pragma unroll
        for (int r = 0; r < RPW; r++) {
            int mrow = wid * RPW + r;
            int row = bid * RPB + mrow;
            float si = s0[row];
            float a0 = wc[0] * si, a1 = wc[1] * si;
            float b0 = wc[2],      b1 = wc[3];
            float num0 = 0.f, den0 = 0.f, num1 = 0.f, den1 = 0.f;
            #pragma unroll
            for (int k = 0; k < 8; k++) {
                unsigned int w = mask[mrow][k * 64 + lane];
                if (!w) continue;
                int jb = (k * 64 + lane) << 3;
                #pragma unroll
                for (int kk = 0; kk < 8; kk++) {
                    unsigned int nib = (w >> (kk * 4)) & 0xFu;
                    if (!nib) continue;
                    float c2 = (float)__popc(nib);
                    float sj = s0[jb + kk];
                    float l0 = c2 * (a0 + b0 * sj) + lut0[nib];
                    l0 = (l0 > 0.f) ? l0 : NEG * l0;
                    float x0 = __expf(l0) - 1.0f;
                    num0 += x0 * sj; den0 += x0;
                    float l1 = c2 * (a1 + b1 * sj) + lut1[nib];
                    l1 = (l1 > 0.f) ? l1 : NEG * l1;
                    float x1 = __expf(l1) - 1.0f;
                    num1 += x1 * sj; den1 += x1;
                }
            }
            #pragma unroll
            for (int off = 32; off > 0; off >>= 1) {
                num0 += __shfl_down(num0, off); den0 += __shfl_down(den0, off);
                num1 += __shfl_down(num1, off); den1 += __shfl_down(den1, off);
            }
            if (lane == 0) {
                float o0 = (S + num0) / ((float)NN + den0);
                float o1 = (S + num1) / ((float)NN + den1);
                s1[row] = 0.5f * (o0 + o1);
            }
        }
    }
    gbar(bar, 2u);

    // ================= P2: layer 1 (reuse LDS masks) ==========================
    if (tid < 16) {
        int h = tid >> 3, m = tid & 7;
        const float* w = att_w + (2 + h) * (DD + 2);   // layer 1
        float e0 = 0.f, e1 = 0.f, e2 = 0.f;
        #pragma unroll
        for (int d = 0; d < DD; d++) {
            float wd = w[1 + d];
            e0 += edge_emb[0 * DD + d] * wd;
            e1 += edge_emb[1 * DD + d] * wd;
            e2 += edge_emb[2 * DD + d] * wd;
        }
        float l = (m & 1 ? e0 : 0.f) + (m & 2 ? e1 : 0.f) + (m & 4 ? e2 : 0.f);
        if (h) lut1[m] = l; else lut0[m] = l;
        if (m == 0) { wc[h] = w[0]; wc[2 + h] = w[DD + 1]; }
    }
    ps = 0.f;
    for (int j = tid; j < NN; j += NTHR) ps += s1[j];
    #pragma unroll
    for (int off = 32; off > 0; off >>= 1) ps += __shfl_down(ps, off);
    __syncthreads();                               // P1 Sred readers done
    if (lane == 0) Sred[wid] = ps;
    __syncthreads();
    {
        float S = 0.f;
        #pragma unroll
        for (int q = 0; q < NWAVE; q++) S += Sred[q];
        #pragma unroll
        for (int r = 0; r < RPW; r++) {
            int mrow = wid * RPW + r;
            int row = bid * RPB + mrow;
            float si = s1[row];
            float a0 = wc[0] * si, a1 = wc[1] * si;
            float b0 = wc[2],      b1 = wc[3];
            float num0 = 0.f, den0 = 0.f, num1 = 0.f, den1 = 0.f;
            #pragma unroll
            for (int k = 0; k < 8; k++) {
                unsigned int w = mask[mrow][k * 64 + lane];
                if (!w) continue;
                int jb = (k * 64 + lane) << 3;
                #pragma unroll
                for (int kk = 0; kk < 8; kk++) {
                    unsigned int nib = (w >> (kk * 4)) & 0xFu;
                    if (!nib) continue;
                    float c2 = (float)__popc(nib);
                    float sj = s1[jb + kk];
                    float l0 = c2 * (a0 + b0 * sj) + lut0[nib];
                    l0 = (l0 > 0.f) ? l0 : NEG * l0;
                    float x0 = __expf(l0) - 1.0f;
                    num0 += x0 * sj; den0 += x0;
                    float l1 = c2 * (a1 + b1 * sj) + lut1[nib];
                    l1 = (l1 > 0.f) ? l1 : NEG * l1;
                    float x1 = __expf(l1) - 1.0f;
                    num1 += x1 * sj; den1 += x1;
                }
            }
            #pragma unroll
            for (int off = 32; off > 0; off >>= 1) {
                num0 += __shfl_down(num0, off); den0 += __shfl_down(den0, off);
                num1 += __shfl_down(num1, off); den1 += __shfl_down(den1, off);
            }
            if (lane == 0) {
                float o0 = (S + num0) / ((float)NN + den0);
                float o1 = (S + num1) / ((float)NN + den1);
                out[row] = 0.5f * (o0 + o1);
            }
        }
    }
}

// ---- host-side launcher ------------------------------------------------------
extern "C" void kernel_launch(void* const* d_in, const int* in_sizes, int n_in,
                              void* d_out, int out_size, void* d_ws, size_t ws_size,
                              hipStream_t stream) {
    const float* inputs   = (const float*)d_in[0];
    const float* lin_w    = (const float*)d_in[1];
    const float* lin_b    = (const float*)d_in[2];
    const float* edge_emb = (const float*)d_in[3];
    const float* att_w    = (const float*)d_in[4];
    const int*   el       = (const int*)d_in[5];
    float* out = (float*)d_out;

    char* ws = (char*)d_ws;
    unsigned int*   cnt    = (unsigned int*)ws;                           // 256 KB (padded)
    unsigned int*   bar    = (unsigned int*)(ws + 262144);                // 8 B
    unsigned short* bucket = (unsigned short*)(ws + 262208);              // 4 MB
    float*          s0     = (float*)(ws + 4456512);                      // 16 KB
    float*          s1     = (float*)(ws + 4472896);                      // 16 KB

    hipMemsetAsync(ws, 0, 262152, stream);         // cnt + barrier words

    void* args[] = { (void*)&el, (void*)&cnt, (void*)&bar, (void*)&bucket,
                     (void*)&inputs, (void*)&lin_w, (void*)&lin_b,
                     (void*)&edge_emb, (void*)&att_w,
                     (void*)&s0, (void*)&s1, (void*)&out };
    hipLaunchCooperativeKernel((const void*)k_fused, dim3(NBLK), dim3(NTHR),
                               args, 0, stream);
}

// Round 14
// 92.928 us; speedup vs baseline: 1.8956x; 1.8956x over previous
//
#include <hip/hip_runtime.h>

#define NN     4096
#define TT     3
#define DD     20
#define EE     131072
#define ADIM   128
#define NEG    0.2f
#define NEDGE  (TT * EE)               // 393216 edges
#define NBINS  128                     // row>>5 -> 32 rows per bin
#define SEG    8192                    // items per bin segment (expect ~6144)
#define EPB    1536                    // edges per k_bin block (256 blocks)
#define CAP    512                     // CSR entries per row (max ~260)

// ---- k_bin: LDS-staged binning by row>>5, coalesced flush + fused s0 init ---
// item = row(12)<<14 | col(12)<<2 | t(2); bin = item>>19.
__global__ __launch_bounds__(256) void k_bin(const int* __restrict__ el,
                                             unsigned int* __restrict__ bincnt,
                                             unsigned int* __restrict__ bigbin,
                                             const float* __restrict__ inputs,
                                             const float* __restrict__ lin_w,
                                             const float* __restrict__ lin_b,
                                             float* __restrict__ s0) {
    __shared__ unsigned int cnt[NBINS], pref[NBINS], base[NBINS];
    __shared__ unsigned int items[2 * EPB];        // 12 KB
    int tid = threadIdx.x, bid = blockIdx.x;

    if (tid < NBINS) cnt[tid] = 0u;
    __syncthreads();

    unsigned int it[12];
    #pragma unroll
    for (int k = 0; k < 6; k++) {                  // 6 edges -> 12 directed items
        int edge = bid * EPB + k * 256 + tid;
        int t = edge >> 17;                        // EE = 2^17
        int e = edge & (EE - 1);
        unsigned int a = (unsigned int)el[(t * 2) * EE + e];
        unsigned int b = (unsigned int)el[(t * 2 + 1) * EE + e];
        it[2 * k]     = (a << 14) | (b << 2) | (unsigned int)t;
        it[2 * k + 1] = (b << 14) | (a << 2) | (unsigned int)t;
        atomicAdd(&cnt[a >> 5], 1u);
        atomicAdd(&cnt[b >> 5], 1u);
    }
    __syncthreads();

    if (tid < 64) {                                // single-wave scan of 128 bins
        unsigned int c0 = cnt[2 * tid], c1 = cnt[2 * tid + 1];
        unsigned int s = c0 + c1, p = s;
        #pragma unroll
        for (int off = 1; off < 64; off <<= 1) {
            unsigned int v = __shfl_up(p, off);
            if (tid >= off) p += v;
        }
        unsigned int ex = p - s;
        pref[2 * tid] = ex; pref[2 * tid + 1] = ex + c0;
    }
    __syncthreads();
    if (tid < NBINS) cnt[tid] = 0u;                // reuse as rank counters
    __syncthreads();

    #pragma unroll
    for (int k = 0; k < 12; k++) {
        unsigned int v = it[k], bin = v >> 19;
        unsigned int r = atomicAdd(&cnt[bin], 1u);
        items[pref[bin] + r] = v;
    }
    __syncthreads();

    if (tid < NBINS)                               // 2 waves of parallel allocs
        base[tid] = atomicAdd(&bincnt[tid], cnt[tid]);
    __syncthreads();

    for (int i = tid; i < 2 * EPB; i += 256) {     // coalesced per-bin runs
        unsigned int v = items[i], bin = v >> 19;
        unsigned int idx = base[bin] + ((unsigned int)i - pref[bin]);
        if (idx < SEG) bigbin[bin * SEG + idx] = v;
    }

    // fused: s0 = inputs @ lin_w.T + lin_b  (1024 waves x 4 rows)
    int wid = tid >> 6, lane = tid & 63;
    int wg = bid * 4 + wid;
    #pragma unroll
    for (int r = 0; r < 4; r++) {
        int row = wg * 4 + r;
        const float* rp = inputs + row * ADIM;
        float v = rp[lane] * lin_w[lane] + rp[lane + 64] * lin_w[lane + 64];
        #pragma unroll
        for (int off = 32; off > 0; off >>= 1) v += __shfl_down(v, off);
        if (lane == 0) s0[row] = v + lin_b[0];
    }
}

// ---- k_l0: block per bin (32 rows) — LDS mask dedup + layer 0 + CSR emit ----
__global__ __launch_bounds__(512) void k_l0(const unsigned int* __restrict__ bincnt,
                                            const unsigned int* __restrict__ bigbin,
                                            unsigned int* __restrict__ cnt2,
                                            unsigned short* __restrict__ entries2,
                                            const float* __restrict__ s_in,
                                            const float* __restrict__ att_w,
                                            const float* __restrict__ edge_emb,
                                            float* __restrict__ s_out) {
    __shared__ unsigned int mask[32][512];         // 64 KB: 32 rows x nibble-mask
    __shared__ float lut0[8], lut1[8], wc[4], Sred[8];
    int tid = threadIdx.x, bid = blockIdx.x;
    int wid = tid >> 6, lane = tid & 63;

    if (tid < 16) {                                // layer 0 constants
        int h = tid >> 3, m = tid & 7;
        const float* w = att_w + h * (DD + 2);
        float e0 = 0.f, e1 = 0.f, e2 = 0.f;
        #pragma unroll
        for (int d = 0; d < DD; d++) {
            float wd = w[1 + d];
            e0 += edge_emb[0 * DD + d] * wd;
            e1 += edge_emb[1 * DD + d] * wd;
            e2 += edge_emb[2 * DD + d] * wd;
        }
        float l = (m & 1 ? e0 : 0.f) + (m & 2 ? e1 : 0.f) + (m & 4 ? e2 : 0.f);
        if (h) lut1[m] = l; else lut0[m] = l;
        if (m == 0) { wc[h] = w[0]; wc[2 + h] = w[DD + 1]; }
    }

    for (int i = tid; i < 32 * 512; i += 512)      // zero 64 KB mask
        ((unsigned int*)mask)[i] = 0u;

    float ps = 0.f;                                // S = sum(s_in)
    for (int j = tid; j < NN; j += 512) ps += s_in[j];
    #pragma unroll
    for (int off = 32; off > 0; off >>= 1) ps += __shfl_down(ps, off);
    if (lane == 0) Sred[wid] = ps;
    __syncthreads();

    unsigned int n = min(bincnt[bid], (unsigned int)SEG);
    const unsigned int* bb = bigbin + (size_t)bid * SEG;
    for (unsigned int i = tid; i < n; i += 512) {  // sequential read + LDS OR
        unsigned int v = bb[i];
        unsigned int lr = (v >> 14) & 31u;
        unsigned int col = (v >> 2) & 0xFFFu;
        unsigned int t = v & 3u;
        atomicOr(&mask[lr][col >> 3], 1u << (((col & 7u) << 2) + t));
    }
    __syncthreads();

    float S = 0.f;
    #pragma unroll
    for (int q = 0; q < 8; q++) S += Sred[q];
    float b0 = wc[2], b1 = wc[3];

    #pragma unroll
    for (int r = 0; r < 4; r++) {                  // 8 waves x 4 rows = 32 rows
        int lr = wid * 4 + r;
        int row = bid * 32 + lr;
        float si = s_in[row];
        float a0 = wc[0] * si, a1 = wc[1] * si;
        unsigned short* erow = entries2 + (size_t)row * CAP;

        float num0 = 0.f, den0 = 0.f, num1 = 0.f, den1 = 0.f;
        unsigned int bpos = 0;
        #pragma unroll
        for (int k = 0; k < 8; k++) {              // 512 words, 8 per lane
            unsigned int w = mask[lr][k * 64 + lane];
            unsigned int y = w | (w >> 1); y |= (y >> 2); y &= 0x11111111u;
            unsigned int cc = __popc(y);
            unsigned int p = cc;                   // wave-inclusive scan
            #pragma unroll
            for (int off = 1; off < 64; off <<= 1) {
                unsigned int v = __shfl_up(p, off);
                if (lane >= off) p += v;
            }
            unsigned int pos = bpos + (p - cc);    // exclusive prefix
            if (w) {
                int jb = (k * 64 + lane) << 3;
                #pragma unroll
                for (int kk = 0; kk < 8; kk++) {
                    unsigned int nib = (w >> (kk * 4)) & 0xFu;
                    if (!nib) continue;
                    int j = jb + kk;
                    float c2 = (float)__popc(nib);
                    float sj = s_in[j];
                    float l0 = c2 * (a0 + b0 * sj) + lut0[nib];
                    l0 = (l0 > 0.f) ? l0 : NEG * l0;
                    float x0 = __expf(l0) - 1.0f;
                    num0 += x0 * sj; den0 += x0;
                    float l1 = c2 * (a1 + b1 * sj) + lut1[nib];
                    l1 = (l1 > 0.f) ? l1 : NEG * l1;
                    float x1 = __expf(l1) - 1.0f;
                    num1 += x1 * sj; den1 += x1;
                    erow[pos++] = (unsigned short)(j | (nib << 12));
                }
            }
            bpos += __shfl(p, 63);
        }
        if (lane == 0) cnt2[row] = bpos;

        #pragma unroll
        for (int off = 32; off > 0; off >>= 1) {
            num0 += __shfl_down(num0, off); den0 += __shfl_down(den0, off);
            num1 += __shfl_down(num1, off); den1 += __shfl_down(den1, off);
        }
        if (lane == 0) {
            float o0 = (S + num0) / ((float)NN + den0);
            float o1 = (S + num1) / ((float)NN + den1);
            s_out[row] = 0.5f * (o0 + o1);
        }
    }
}

// ---- k_l1: layer 1 over compact CSR (row per wave) --------------------------
__global__ __launch_bounds__(256) void k_l1(const unsigned int* __restrict__ cnt2,
                                            const unsigned short* __restrict__ entries2,
                                            const float* __restrict__ s_in,
                                            const float* __restrict__ att_w,
                                            const float* __restrict__ edge_emb,
                                            float* __restrict__ s_out) {
    __shared__ float lut0[8], lut1[8], wc[4], Sred[4];
    int tid = threadIdx.x;

    if (tid < 16) {                                // layer 1 constants
        int h = tid >> 3, m = tid & 7;
        const float* w = att_w + (2 + h) * (DD + 2);
        float e0 = 0.f, e1 = 0.f, e2 = 0.f;
        #pragma unroll
        for (int d = 0; d < DD; d++) {
            float wd = w[1 + d];
            e0 += edge_emb[0 * DD + d] * wd;
            e1 += edge_emb[1 * DD + d] * wd;
            e2 += edge_emb[2 * DD + d] * wd;
        }
        float l = (m & 1 ? e0 : 0.f) + (m & 2 ? e1 : 0.f) + (m & 4 ? e2 : 0.f);
        if (h) lut1[m] = l; else lut0[m] = l;
        if (m == 0) { wc[h] = w[0]; wc[2 + h] = w[DD + 1]; }
    }

    float ps = 0.f;
    for (int j = tid; j < NN; j += 256) ps += s_in[j];
    #pragma unroll
    for (int off = 32; off > 0; off >>= 1) ps += __shfl_down(ps, off);
    int wid = tid >> 6, lane = tid & 63;
    if (lane == 0) Sred[wid] = ps;
    __syncthreads();
    float S = Sred[0] + Sred[1] + Sred[2] + Sred[3];

    int row = blockIdx.x * 4 + wid;
    float si = s_in[row];
    float a0 = wc[0] * si, a1 = wc[1] * si;
    float b0 = wc[2],      b1 = wc[3];
    unsigned int n = cnt2[row];
    const unsigned short* ent = entries2 + (size_t)row * CAP;

    float num0 = 0.f, den0 = 0.f, num1 = 0.f, den1 = 0.f;
    for (unsigned int i = lane; i < n; i += 64) {
        unsigned int v = ent[i];
        unsigned int j = v & 0xFFFu, nib = v >> 12;
        float c  = (float)__popc(nib);
        float sj = s_in[j];
        float l0 = c * (a0 + b0 * sj) + lut0[nib];
        l0 = (l0 > 0.f) ? l0 : NEG * l0;
        float x0 = __expf(l0) - 1.0f;
        num0 += x0 * sj; den0 += x0;
        float l1 = c * (a1 + b1 * sj) + lut1[nib];
        l1 = (l1 > 0.f) ? l1 : NEG * l1;
        float x1 = __expf(l1) - 1.0f;
        num1 += x1 * sj; den1 += x1;
    }

    #pragma unroll
    for (int off = 32; off > 0; off >>= 1) {
        num0 += __shfl_down(num0, off); den0 += __shfl_down(den0, off);
        num1 += __shfl_down(num1, off); den1 += __shfl_down(den1, off);
    }
    if (lane == 0) {
        float o0 = (S + num0) / ((float)NN + den0);
        float o1 = (S + num1) / ((float)NN + den1);
        s_out[row] = 0.5f * (o0 + o1);
    }
}

// ---- host-side launcher ------------------------------------------------------
extern "C" void kernel_launch(void* const* d_in, const int* in_sizes, int n_in,
                              void* d_out, int out_size, void* d_ws, size_t ws_size,
                              hipStream_t stream) {
    const float* inputs   = (const float*)d_in[0];
    const float* lin_w    = (const float*)d_in[1];
    const float* lin_b    = (const float*)d_in[2];
    const float* edge_emb = (const float*)d_in[3];
    const float* att_w    = (const float*)d_in[4];
    const int*   el       = (const int*)d_in[5];
    float* out = (float*)d_out;

    char* ws = (char*)d_ws;
    unsigned int*   bincnt   = (unsigned int*)ws;                         // 512 B
    unsigned int*   bigbin   = (unsigned int*)(ws + 4096);                // 4 MB
    unsigned short* entries2 = (unsigned short*)(ws + 4198400);           // 4 MB
    unsigned int*   cnt2     = (unsigned int*)(ws + 8392704);             // 16 KB
    float*          s0       = (float*)(ws + 8409088);                    // 16 KB
    float*          s1       = (float*)(ws + 8425472);                    // 16 KB

    hipMemsetAsync(bincnt, 0, NBINS * sizeof(unsigned int), stream);
    k_bin<<<256, 256, 0, stream>>>(el, bincnt, bigbin, inputs, lin_w, lin_b, s0);
    k_l0 <<<NBINS, 512, 0, stream>>>(bincnt, bigbin, cnt2, entries2,
                                     s0, att_w, edge_emb, s1);
    k_l1 <<<1024, 256, 0, stream>>>(cnt2, entries2, s1, att_w, edge_emb, out);
}

// Round 15
// 55.417 us; speedup vs baseline: 3.1787x; 1.6769x over previous
//
#include <hip/hip_runtime.h>

#define NN     4096
#define TT     3
#define DD     20
#define EE     131072
#define ADIM   128
#define NEG    0.2f
#define NEDGE  (TT * EE)               // 393216 edges
#define NBINS  512                     // row>>3 -> 8 rows per bin
#define RPB2   8
#define SEG    3072                    // items per bin segment (mean ~1536)
#define EPB    1536                    // edges per k_bin block (256 blocks)
#define CAP    512                     // CSR entries per row (max ~260)

// item = row(12)<<14 | col(12)<<2 | t(2);  bin = item>>17 (row>>3)

// ---- k_bin: LDS-staged binning, coalesced flush + fused s0 init -------------
__global__ __launch_bounds__(256) void k_bin(const int* __restrict__ el,
                                             unsigned int* __restrict__ bincnt,
                                             unsigned int* __restrict__ bigbin,
                                             const float* __restrict__ inputs,
                                             const float* __restrict__ lin_w,
                                             const float* __restrict__ lin_b,
                                             float* __restrict__ s0) {
    __shared__ unsigned int cnt[NBINS], pref[NBINS], base[NBINS];
    __shared__ unsigned int items[2 * EPB];        // 12 KB
    __shared__ unsigned int wtot[4], wo[4];
    int tid = threadIdx.x, bid = blockIdx.x;
    int lane = tid & 63, wid = tid >> 6;

    cnt[2 * tid] = 0u; cnt[2 * tid + 1] = 0u;
    __syncthreads();

    unsigned int it[12];
    #pragma unroll
    for (int k = 0; k < 6; k++) {                  // 6 edges -> 12 directed items
        int edge = bid * EPB + k * 256 + tid;
        int t = edge >> 17;                        // EE = 2^17
        int e = edge & (EE - 1);
        unsigned int a = (unsigned int)el[(t * 2) * EE + e];
        unsigned int b = (unsigned int)el[(t * 2 + 1) * EE + e];
        it[2 * k]     = (a << 14) | (b << 2) | (unsigned int)t;
        it[2 * k + 1] = (b << 14) | (a << 2) | (unsigned int)t;
        atomicAdd(&cnt[a >> 3], 1u);
        atomicAdd(&cnt[b >> 3], 1u);
    }
    __syncthreads();

    // block scan of 512 bin counts (2 per thread)
    unsigned int c0 = cnt[2 * tid], c1 = cnt[2 * tid + 1];
    unsigned int s = c0 + c1, p = s;
    #pragma unroll
    for (int off = 1; off < 64; off <<= 1) {
        unsigned int v = __shfl_up(p, off);
        if (lane >= off) p += v;
    }
    if (lane == 63) wtot[wid] = p;
    __syncthreads();
    if (tid == 0) { unsigned int r = 0;
        #pragma unroll
        for (int q = 0; q < 4; q++) { wo[q] = r; r += wtot[q]; } }
    __syncthreads();
    unsigned int ex = wo[wid] + (p - s);
    pref[2 * tid] = ex; pref[2 * tid + 1] = ex + c0;
    __syncthreads();
    cnt[2 * tid] = 0u; cnt[2 * tid + 1] = 0u;      // reuse as rank counters
    __syncthreads();

    #pragma unroll
    for (int k = 0; k < 12; k++) {
        unsigned int v = it[k], bin = v >> 17;
        unsigned int r = atomicAdd(&cnt[bin], 1u);
        items[pref[bin] + r] = v;
    }
    __syncthreads();

    for (int i = tid; i < NBINS; i += 256)
        base[i] = atomicAdd(&bincnt[i], cnt[i]);
    __syncthreads();

    for (int i = tid; i < 2 * EPB; i += 256) {     // coalesced per-bin runs
        unsigned int v = items[i], bin = v >> 17;
        unsigned int idx = base[bin] + ((unsigned int)i - pref[bin]);
        if (idx < SEG) bigbin[bin * SEG + idx] = v;
    }

    // fused: s0 = inputs @ lin_w.T + lin_b  (256 blocks x 4 waves x 4 rows)
    int wg = bid * 4 + wid;
    #pragma unroll
    for (int r = 0; r < 4; r++) {
        int row = wg * 4 + r;
        const float* rp = inputs + row * ADIM;
        float v = rp[lane] * lin_w[lane] + rp[lane + 64] * lin_w[lane + 64];
        #pragma unroll
        for (int off = 32; off > 0; off >>= 1) v += __shfl_down(v, off);
        if (lane == 0) s0[row] = v + lin_b[0];
    }
}

// ---- k_l0: bin per block (8 rows) — OR-build then AND-claim dedup -----------
__global__ __launch_bounds__(256) void k_l0(const unsigned int* __restrict__ bincnt,
                                            const unsigned int* __restrict__ bigbin,
                                            unsigned int* __restrict__ cnt2,
                                            unsigned short* __restrict__ entries2,
                                            const float* __restrict__ s_in,
                                            const float* __restrict__ att_w,
                                            const float* __restrict__ edge_emb,
                                            float* __restrict__ s_out) {
    __shared__ unsigned int mask[RPB2][512];       // 16 KB nibble-mask
    __shared__ float accf[RPB2][4];
    __shared__ unsigned int rcnt[RPB2];
    __shared__ float lut0[8], lut1[8], wc4[4], Sred[4], arow[RPB2][2];
    int tid = threadIdx.x, bid = blockIdx.x;
    int lane = tid & 63, wid = tid >> 6;

    if (tid < 16) {                                // layer 0 constants
        int h = tid >> 3, m = tid & 7;
        const float* w = att_w + h * (DD + 2);
        float e0 = 0.f, e1 = 0.f, e2 = 0.f;
        #pragma unroll
        for (int d = 0; d < DD; d++) {
            float wd = w[1 + d];
            e0 += edge_emb[0 * DD + d] * wd;
            e1 += edge_emb[1 * DD + d] * wd;
            e2 += edge_emb[2 * DD + d] * wd;
        }
        float l = (m & 1 ? e0 : 0.f) + (m & 2 ? e1 : 0.f) + (m & 4 ? e2 : 0.f);
        if (h) lut1[m] = l; else lut0[m] = l;
        if (m == 0) { wc4[h] = w[0]; wc4[2 + h] = w[DD + 1]; }
    }
    if (tid < RPB2) rcnt[tid] = 0u;
    if (tid < RPB2 * 4) ((float*)accf)[tid] = 0.f;
    #pragma unroll
    for (int i = 0; i < 16; i++)                   // zero 16 KB mask
        ((unsigned int*)mask)[i * 256 + tid] = 0u;

    float ps = 0.f;                                // S = sum(s_in)
    #pragma unroll
    for (int i = 0; i < 16; i++) ps += s_in[i * 256 + tid];
    #pragma unroll
    for (int off = 32; off > 0; off >>= 1) ps += __shfl_down(ps, off);
    if (lane == 0) Sred[wid] = ps;
    __syncthreads();
    float S = Sred[0] + Sred[1] + Sred[2] + Sred[3];
    if (tid < RPB2) {                              // per-row a-terms
        float si = s_in[bid * RPB2 + tid];
        arow[tid][0] = wc4[0] * si;
        arow[tid][1] = wc4[1] * si;
    }

    unsigned int n = min(bincnt[bid], (unsigned int)SEG);
    const unsigned int* bb = bigbin + (size_t)bid * SEG;
    for (unsigned int i = tid; i < n; i += 256) {  // pass 1: build mask
        unsigned int v = bb[i];
        unsigned int lr = (v >> 14) & 7u;
        unsigned int col = (v >> 2) & 0xFFFu;
        unsigned int t = v & 3u;
        atomicOr(&mask[lr][col >> 3], 1u << (((col & 7u) << 2) + t));
    }
    __syncthreads();                               // mask + arow ready

    float b0 = wc4[2], b1 = wc4[3];
    for (unsigned int i = tid; i < n; i += 256) {  // pass 2: claim & compute
        unsigned int v = bb[i];
        unsigned int lr = (v >> 14) & 7u;
        unsigned int col = (v >> 2) & 0xFFFu;
        unsigned int sh = (col & 7u) << 2;
        unsigned int old = atomicAnd(&mask[lr][col >> 3], ~(0xFu << sh));
        unsigned int nib = (old >> sh) & 0xFu;
        if (nib) {                                 // unique owner of this pair
            float c2 = (float)__popc(nib);
            float sj = s_in[col];
            float l0 = c2 * (arow[lr][0] + b0 * sj) + lut0[nib];
            l0 = (l0 > 0.f) ? l0 : NEG * l0;
            float x0 = __expf(l0) - 1.0f;
            float l1 = c2 * (arow[lr][1] + b1 * sj) + lut1[nib];
            l1 = (l1 > 0.f) ? l1 : NEG * l1;
            float x1 = __expf(l1) - 1.0f;
            atomicAdd(&accf[lr][0], x0 * sj);
            atomicAdd(&accf[lr][1], x0);
            atomicAdd(&accf[lr][2], x1 * sj);
            atomicAdd(&accf[lr][3], x1);
            unsigned int r = atomicAdd(&rcnt[lr], 1u);
            entries2[(size_t)(bid * RPB2 + lr) * CAP + r] =
                (unsigned short)(col | (nib << 12));
        }
    }
    __syncthreads();

    if (tid < RPB2) {
        int row = bid * RPB2 + tid;
        float o0 = (S + accf[tid][0]) / ((float)NN + accf[tid][1]);
        float o1 = (S + accf[tid][2]) / ((float)NN + accf[tid][3]);
        s_out[row] = 0.5f * (o0 + o1);
        cnt2[row] = rcnt[tid];
    }
}

// ---- k_l1: layer 1 over compact CSR (row per wave) --------------------------
__global__ __launch_bounds__(256) void k_l1(const unsigned int* __restrict__ cnt2,
                                            const unsigned short* __restrict__ entries2,
                                            const float* __restrict__ s_in,
                                            const float* __restrict__ att_w,
                                            const float* __restrict__ edge_emb,
                                            float* __restrict__ s_out) {
    __shared__ float lut0[8], lut1[8], wc4[4], Sred[4];
    int tid = threadIdx.x;

    if (tid < 16) {                                // layer 1 constants
        int h = tid >> 3, m = tid & 7;
        const float* w = att_w + (2 + h) * (DD + 2);
        float e0 = 0.f, e1 = 0.f, e2 = 0.f;
        #pragma unroll
        for (int d = 0; d < DD; d++) {
            float wd = w[1 + d];
            e0 += edge_emb[0 * DD + d] * wd;
            e1 += edge_emb[1 * DD + d] * wd;
            e2 += edge_emb[2 * DD + d] * wd;
        }
        float l = (m & 1 ? e0 : 0.f) + (m & 2 ? e1 : 0.f) + (m & 4 ? e2 : 0.f);
        if (h) lut1[m] = l; else lut0[m] = l;
        if (m == 0) { wc4[h] = w[0]; wc4[2 + h] = w[DD + 1]; }
    }

    float ps = 0.f;
    for (int j = tid; j < NN; j += 256) ps += s_in[j];
    #pragma unroll
    for (int off = 32; off > 0; off >>= 1) ps += __shfl_down(ps, off);
    int wid = tid >> 6, lane = tid & 63;
    if (lane == 0) Sred[wid] = ps;
    __syncthreads();
    float S = Sred[0] + Sred[1] + Sred[2] + Sred[3];

    int row = blockIdx.x * 4 + wid;
    float si = s_in[row];
    float a0 = wc4[0] * si, a1 = wc4[1] * si;
    float b0 = wc4[2],      b1 = wc4[3];
    unsigned int n = cnt2[row];
    const unsigned short* ent = entries2 + (size_t)row * CAP;

    float num0 = 0.f, den0 = 0.f, num1 = 0.f, den1 = 0.f;
    for (unsigned int i = lane; i < n; i += 64) {
        unsigned int v = ent[i];
        unsigned int j = v & 0xFFFu, nib = v >> 12;
        float c  = (float)__popc(nib);
        float sj = s_in[j];
        float l0 = c * (a0 + b0 * sj) + lut0[nib];
        l0 = (l0 > 0.f) ? l0 : NEG * l0;
        float x0 = __expf(l0) - 1.0f;
        num0 += x0 * sj; den0 += x0;
        float l1 = c * (a1 + b1 * sj) + lut1[nib];
        l1 = (l1 > 0.f) ? l1 : NEG * l1;
        float x1 = __expf(l1) - 1.0f;
        num1 += x1 * sj; den1 += x1;
    }

    #pragma unroll
    for (int off = 32; off > 0; off >>= 1) {
        num0 += __shfl_down(num0, off); den0 += __shfl_down(den0, off);
        num1 += __shfl_down(num1, off); den1 += __shfl_down(den1, off);
    }
    if (lane == 0) {
        float o0 = (S + num0) / ((float)NN + den0);
        float o1 = (S + num1) / ((float)NN + den1);
        s_out[row] = 0.5f * (o0 + o1);
    }
}

// ---- host-side launcher ------------------------------------------------------
extern "C" void kernel_launch(void* const* d_in, const int* in_sizes, int n_in,
                              void* d_out, int out_size, void* d_ws, size_t ws_size,
                              hipStream_t stream) {
    const float* inputs   = (const float*)d_in[0];
    const float* lin_w    = (const float*)d_in[1];
    const float* lin_b    = (const float*)d_in[2];
    const float* edge_emb = (const float*)d_in[3];
    const float* att_w    = (const float*)d_in[4];
    const int*   el       = (const int*)d_in[5];
    float* out = (float*)d_out;

    char* ws = (char*)d_ws;
    unsigned int*   bincnt   = (unsigned int*)ws;                         // 2 KB
    unsigned int*   bigbin   = (unsigned int*)(ws + 4096);                // 6 MB
    unsigned short* entries2 = (unsigned short*)(ws + 6295552);           // 4 MB
    unsigned int*   cnt2     = (unsigned int*)(ws + 10489856);            // 16 KB
    float*          s0       = (float*)(ws + 10506240);                   // 16 KB
    float*          s1       = (float*)(ws + 10522624);                   // 16 KB

    hipMemsetAsync(bincnt, 0, NBINS * sizeof(unsigned int), stream);
    k_bin<<<256, 256, 0, stream>>>(el, bincnt, bigbin, inputs, lin_w, lin_b, s0);
    k_l0 <<<NBINS, 256, 0, stream>>>(bincnt, bigbin, cnt2, entries2,
                                     s0, att_w, edge_emb, s1);
    k_l1 <<<1024, 256, 0, stream>>>(cnt2, entries2, s1, att_w, edge_emb, out);
}

// Round 16
// 55.281 us; speedup vs baseline: 3.1865x; 1.0025x over previous
//
#include <hip/hip_runtime.h>

#define NN     4096
#define TT     3
#define DD     20
#define EE     131072
#define ADIM   128
#define NEG    0.2f
#define NEDGE  (TT * EE)               // 393216 edges
#define NBINS  512                     // row>>3 -> 8 rows per bin
#define RPB2   8
#define SEG    3072                    // items per bin segment (mean ~1536)
#define EPB    1536                    // edges per k_bin block (256 blocks)
#define CAP    512                     // CSR entries per row (max ~260)

// item = row(12)<<14 | col(12)<<2 | t(2);  bin = item>>17 (row>>3)

// ---- k_zero: replace hipMemsetAsync (rocclr fill costs ~39 us fixed!) -------
__global__ __launch_bounds__(512) void k_zero(unsigned int* __restrict__ bincnt) {
    bincnt[threadIdx.x] = 0u;                      // exactly NBINS threads
}

// ---- k_bin: LDS-staged binning, coalesced flush + fused s0 init -------------
__global__ __launch_bounds__(256) void k_bin(const int* __restrict__ el,
                                             unsigned int* __restrict__ bincnt,
                                             unsigned int* __restrict__ bigbin,
                                             const float* __restrict__ inputs,
                                             const float* __restrict__ lin_w,
                                             const float* __restrict__ lin_b,
                                             float* __restrict__ s0) {
    __shared__ unsigned int cnt[NBINS], pref[NBINS], base[NBINS];
    __shared__ unsigned int items[2 * EPB];        // 12 KB
    __shared__ unsigned int wtot[4], wo[4];
    int tid = threadIdx.x, bid = blockIdx.x;
    int lane = tid & 63, wid = tid >> 6;

    cnt[2 * tid] = 0u; cnt[2 * tid + 1] = 0u;
    __syncthreads();

    unsigned int it[12];
    #pragma unroll
    for (int k = 0; k < 6; k++) {                  // 6 edges -> 12 directed items
        int edge = bid * EPB + k * 256 + tid;
        int t = edge >> 17;                        // EE = 2^17
        int e = edge & (EE - 1);
        unsigned int a = (unsigned int)el[(t * 2) * EE + e];
        unsigned int b = (unsigned int)el[(t * 2 + 1) * EE + e];
        it[2 * k]     = (a << 14) | (b << 2) | (unsigned int)t;
        it[2 * k + 1] = (b << 14) | (a << 2) | (unsigned int)t;
        atomicAdd(&cnt[a >> 3], 1u);
        atomicAdd(&cnt[b >> 3], 1u);
    }
    __syncthreads();

    // block scan of 512 bin counts (2 per thread)
    unsigned int c0 = cnt[2 * tid], c1 = cnt[2 * tid + 1];
    unsigned int s = c0 + c1, p = s;
    #pragma unroll
    for (int off = 1; off < 64; off <<= 1) {
        unsigned int v = __shfl_up(p, off);
        if (lane >= off) p += v;
    }
    if (lane == 63) wtot[wid] = p;
    __syncthreads();
    if (tid == 0) { unsigned int r = 0;
        #pragma unroll
        for (int q = 0; q < 4; q++) { wo[q] = r; r += wtot[q]; } }
    __syncthreads();
    unsigned int ex = wo[wid] + (p - s);
    pref[2 * tid] = ex; pref[2 * tid + 1] = ex + c0;
    __syncthreads();
    cnt[2 * tid] = 0u; cnt[2 * tid + 1] = 0u;      // reuse as rank counters
    __syncthreads();

    #pragma unroll
    for (int k = 0; k < 12; k++) {
        unsigned int v = it[k], bin = v >> 17;
        unsigned int r = atomicAdd(&cnt[bin], 1u);
        items[pref[bin] + r] = v;
    }
    __syncthreads();

    for (int i = tid; i < NBINS; i += 256)
        base[i] = atomicAdd(&bincnt[i], cnt[i]);
    __syncthreads();

    for (int i = tid; i < 2 * EPB; i += 256) {     // coalesced per-bin runs
        unsigned int v = items[i], bin = v >> 17;
        unsigned int idx = base[bin] + ((unsigned int)i - pref[bin]);
        if (idx < SEG) bigbin[bin * SEG + idx] = v;
    }

    // fused: s0 = inputs @ lin_w.T + lin_b  (256 blocks x 4 waves x 4 rows)
    int wg = bid * 4 + wid;
    #pragma unroll
    for (int r = 0; r < 4; r++) {
        int row = wg * 4 + r;
        const float* rp = inputs + row * ADIM;
        float v = rp[lane] * lin_w[lane] + rp[lane + 64] * lin_w[lane + 64];
        #pragma unroll
        for (int off = 32; off > 0; off >>= 1) v += __shfl_down(v, off);
        if (lane == 0) s0[row] = v + lin_b[0];
    }
}

// ---- k_l0: bin per block (8 rows) — OR-build then AND-claim dedup -----------
__global__ __launch_bounds__(256) void k_l0(const unsigned int* __restrict__ bincnt,
                                            const unsigned int* __restrict__ bigbin,
                                            unsigned int* __restrict__ cnt2,
                                            unsigned short* __restrict__ entries2,
                                            const float* __restrict__ s_in,
                                            const float* __restrict__ att_w,
                                            const float* __restrict__ edge_emb,
                                            float* __restrict__ s_out) {
    __shared__ unsigned int mask[RPB2][512];       // 16 KB nibble-mask
    __shared__ float accf[RPB2][4];
    __shared__ unsigned int rcnt[RPB2];
    __shared__ float lut0[8], lut1[8], wc4[4], Sred[4], arow[RPB2][2];
    int tid = threadIdx.x, bid = blockIdx.x;
    int lane = tid & 63, wid = tid >> 6;

    if (tid < 16) {                                // layer 0 constants
        int h = tid >> 3, m = tid & 7;
        const float* w = att_w + h * (DD + 2);
        float e0 = 0.f, e1 = 0.f, e2 = 0.f;
        #pragma unroll
        for (int d = 0; d < DD; d++) {
            float wd = w[1 + d];
            e0 += edge_emb[0 * DD + d] * wd;
            e1 += edge_emb[1 * DD + d] * wd;
            e2 += edge_emb[2 * DD + d] * wd;
        }
        float l = (m & 1 ? e0 : 0.f) + (m & 2 ? e1 : 0.f) + (m & 4 ? e2 : 0.f);
        if (h) lut1[m] = l; else lut0[m] = l;
        if (m == 0) { wc4[h] = w[0]; wc4[2 + h] = w[DD + 1]; }
    }
    if (tid < RPB2) rcnt[tid] = 0u;
    if (tid < RPB2 * 4) ((float*)accf)[tid] = 0.f;
    #pragma unroll
    for (int i = 0; i < 16; i++)                   // zero 16 KB mask
        ((unsigned int*)mask)[i * 256 + tid] = 0u;

    float ps = 0.f;                                // S = sum(s_in)
    #pragma unroll
    for (int i = 0; i < 16; i++) ps += s_in[i * 256 + tid];
    #pragma unroll
    for (int off = 32; off > 0; off >>= 1) ps += __shfl_down(ps, off);
    if (lane == 0) Sred[wid] = ps;
    __syncthreads();
    float S = Sred[0] + Sred[1] + Sred[2] + Sred[3];
    if (tid < RPB2) {                              // per-row a-terms
        float si = s_in[bid * RPB2 + tid];
        arow[tid][0] = wc4[0] * si;
        arow[tid][1] = wc4[1] * si;
    }

    unsigned int n = min(bincnt[bid], (unsigned int)SEG);
    const unsigned int* bb = bigbin + (size_t)bid * SEG;
    for (unsigned int i = tid; i < n; i += 256) {  // pass 1: build mask
        unsigned int v = bb[i];
        unsigned int lr = (v >> 14) & 7u;
        unsigned int col = (v >> 2) & 0xFFFu;
        unsigned int t = v & 3u;
        atomicOr(&mask[lr][col >> 3], 1u << (((col & 7u) << 2) + t));
    }
    __syncthreads();                               // mask + arow ready

    float b0 = wc4[2], b1 = wc4[3];
    for (unsigned int i = tid; i < n; i += 256) {  // pass 2: claim & compute
        unsigned int v = bb[i];
        unsigned int lr = (v >> 14) & 7u;
        unsigned int col = (v >> 2) & 0xFFFu;
        unsigned int sh = (col & 7u) << 2;
        unsigned int old = atomicAnd(&mask[lr][col >> 3], ~(0xFu << sh));
        unsigned int nib = (old >> sh) & 0xFu;
        if (nib) {                                 // unique owner of this pair
            float c2 = (float)__popc(nib);
            float sj = s_in[col];
            float l0 = c2 * (arow[lr][0] + b0 * sj) + lut0[nib];
            l0 = (l0 > 0.f) ? l0 : NEG * l0;
            float x0 = __expf(l0) - 1.0f;
            float l1 = c2 * (arow[lr][1] + b1 * sj) + lut1[nib];
            l1 = (l1 > 0.f) ? l1 : NEG * l1;
            float x1 = __expf(l1) - 1.0f;
            atomicAdd(&accf[lr][0], x0 * sj);
            atomicAdd(&accf[lr][1], x0);
            atomicAdd(&accf[lr][2], x1 * sj);
            atomicAdd(&accf[lr][3], x1);
            unsigned int r = atomicAdd(&rcnt[lr], 1u);
            entries2[(size_t)(bid * RPB2 + lr) * CAP + r] =
                (unsigned short)(col | (nib << 12));
        }
    }
    __syncthreads();

    if (tid < RPB2) {
        int row = bid * RPB2 + tid;
        float o0 = (S + accf[tid][0]) / ((float)NN + accf[tid][1]);
        float o1 = (S + accf[tid][2]) / ((float)NN + accf[tid][3]);
        s_out[row] = 0.5f * (o0 + o1);
        cnt2[row] = rcnt[tid];
    }
}

// ---- k_l1: layer 1 over compact CSR (row per wave) --------------------------
__global__ __launch_bounds__(256) void k_l1(const unsigned int* __restrict__ cnt2,
                                            const unsigned short* __restrict__ entries2,
                                            const float* __restrict__ s_in,
                                            const float* __restrict__ att_w,
                                            const float* __restrict__ edge_emb,
                                            float* __restrict__ s_out) {
    __shared__ float lut0[8], lut1[8], wc4[4], Sred[4];
    int tid = threadIdx.x;

    if (tid < 16) {                                // layer 1 constants
        int h = tid >> 3, m = tid & 7;
        const float* w = att_w + (2 + h) * (DD + 2);
        float e0 = 0.f, e1 = 0.f, e2 = 0.f;
        #pragma unroll
        for (int d = 0; d < DD; d++) {
            float wd = w[1 + d];
            e0 += edge_emb[0 * DD + d] * wd;
            e1 += edge_emb[1 * DD + d] * wd;
            e2 += edge_emb[2 * DD + d] * wd;
        }
        float l = (m & 1 ? e0 : 0.f) + (m & 2 ? e1 : 0.f) + (m & 4 ? e2 : 0.f);
        if (h) lut1[m] = l; else lut0[m] = l;
        if (m == 0) { wc4[h] = w[0]; wc4[2 + h] = w[DD + 1]; }
    }

    float ps = 0.f;
    for (int j = tid; j < NN; j += 256) ps += s_in[j];
    #pragma unroll
    for (int off = 32; off > 0; off >>= 1) ps += __shfl_down(ps, off);
    int wid = tid >> 6, lane = tid & 63;
    if (lane == 0) Sred[wid] = ps;
    __syncthreads();
    float S = Sred[0] + Sred[1] + Sred[2] + Sred[3];

    int row = blockIdx.x * 4 + wid;
    float si = s_in[row];
    float a0 = wc4[0] * si, a1 = wc4[1] * si;
    float b0 = wc4[2],      b1 = wc4[3];
    unsigned int n = cnt2[row];
    const unsigned short* ent = entries2 + (size_t)row * CAP;

    float num0 = 0.f, den0 = 0.f, num1 = 0.f, den1 = 0.f;
    for (unsigned int i = lane; i < n; i += 64) {
        unsigned int v = ent[i];
        unsigned int j = v & 0xFFFu, nib = v >> 12;
        float c  = (float)__popc(nib);
        float sj = s_in[j];
        float l0 = c * (a0 + b0 * sj) + lut0[nib];
        l0 = (l0 > 0.f) ? l0 : NEG * l0;
        float x0 = __expf(l0) - 1.0f;
        num0 += x0 * sj; den0 += x0;
        float l1 = c * (a1 + b1 * sj) + lut1[nib];
        l1 = (l1 > 0.f) ? l1 : NEG * l1;
        float x1 = __expf(l1) - 1.0f;
        num1 += x1 * sj; den1 += x1;
    }

    #pragma unroll
    for (int off = 32; off > 0; off >>= 1) {
        num0 += __shfl_down(num0, off); den0 += __shfl_down(den0, off);
        num1 += __shfl_down(num1, off); den1 += __shfl_down(den1, off);
    }
    if (lane == 0) {
        float o0 = (S + num0) / ((float)NN + den0);
        float o1 = (S + num1) / ((float)NN + den1);
        s_out[row] = 0.5f * (o0 + o1);
    }
}

// ---- host-side launcher ------------------------------------------------------
extern "C" void kernel_launch(void* const* d_in, const int* in_sizes, int n_in,
                              void* d_out, int out_size, void* d_ws, size_t ws_size,
                              hipStream_t stream) {
    const float* inputs   = (const float*)d_in[0];
    const float* lin_w    = (const float*)d_in[1];
    const float* lin_b    = (const float*)d_in[2];
    const float* edge_emb = (const float*)d_in[3];
    const float* att_w    = (const float*)d_in[4];
    const int*   el       = (const int*)d_in[5];
    float* out = (float*)d_out;

    char* ws = (char*)d_ws;
    unsigned int*   bincnt   = (unsigned int*)ws;                         // 2 KB
    unsigned int*   bigbin   = (unsigned int*)(ws + 4096);                // 6 MB
    unsigned short* entries2 = (unsigned short*)(ws + 6295552);           // 4 MB
    unsigned int*   cnt2     = (unsigned int*)(ws + 10489856);            // 16 KB
    float*          s0       = (float*)(ws + 10506240);                   // 16 KB
    float*          s1       = (float*)(ws + 10522624);                   // 16 KB

    k_zero<<<1, NBINS, 0, stream>>>(bincnt);
    k_bin <<<256, 256, 0, stream>>>(el, bincnt, bigbin, inputs, lin_w, lin_b, s0);
    k_l0  <<<NBINS, 256, 0, stream>>>(bincnt, bigbin, cnt2, entries2,
                                      s0, att_w, edge_emb, s1);
    k_l1  <<<1024, 256, 0, stream>>>(cnt2, entries2, s1, att_w, edge_emb, out);
}